// Round 1
// baseline (423.466 us; speedup 1.0000x reference)
//
#include <hip/hip_runtime.h>
#include <stdint.h>

// Problem constants
#define B_SZ 32
#define F_SZ 40
#define NB_SZ 36
#define R_SZ 512
#define H_SZ 512
#define D_SZ 1536
#define M1 (B_SZ * F_SZ * NB_SZ)   // 46080
#define NROW (B_SZ * F_SZ)         // 1280
#define FNB (F_SZ * NB_SZ)         // 1440

typedef __attribute__((ext_vector_type(8))) short short8;   // 8 bf16 = 4 VGPRs (MFMA A/B frag)
typedef __attribute__((ext_vector_type(4))) float f32x4;    // MFMA C/D frag

__device__ __forceinline__ unsigned short f2bf(float f) {
    unsigned int x = __float_as_uint(f);
    return (unsigned short)((x + 0x7fffu + ((x >> 16) & 1u)) >> 16);  // RNE
}
__device__ __forceinline__ float bf2f(unsigned short u) {
    union { unsigned int i; float f; } v; v.i = ((unsigned int)u) << 16; return v.f;
}
__device__ __forceinline__ short8 cvt8(float4 f0, float4 f1) {
    short8 r;
    r[0]=(short)f2bf(f0.x); r[1]=(short)f2bf(f0.y); r[2]=(short)f2bf(f0.z); r[3]=(short)f2bf(f0.w);
    r[4]=(short)f2bf(f1.x); r[5]=(short)f2bf(f1.y); r[6]=(short)f2bf(f1.z); r[7]=(short)f2bf(f1.w);
    return r;
}
__device__ __forceinline__ float fast_rcp(float x) {
    float r; asm("v_rcp_f32 %0, %1" : "=v"(r) : "v"(x)); return r;
}
// tanh(x) = (e^{2x}-1)/(e^{2x}+1); clamp so e never overflows. ~1e-6 rel err.
__device__ __forceinline__ float fast_tanh(float x) {
    float cx = fminf(fmaxf(x, -9.0f), 9.0f);
    float e = __expf(2.0f * cx);
    return (e - 1.0f) * fast_rcp(e + 1.0f);
}

// ---------------------------------------------------------------------------
// Wsb = bf16(Wsf)  (512x512)
// ---------------------------------------------------------------------------
__global__ __launch_bounds__(256) void k_cast(
    const float* __restrict__ Wsf, unsigned short* __restrict__ Wsb)
{
    int i = (blockIdx.x * 256 + threadIdx.x) * 8;
    float4 f0 = *(const float4*)(Wsf + i);
    float4 f1 = *(const float4*)(Wsf + i + 4);
    *(short8*)(Wsb + i) = cvt8(f0, f1);
}

// ---------------------------------------------------------------------------
// hs[b,h] = hidden[b]@Ws_h.T + bs_h + bs_f ; hr[b,h] = hidden[b]@Wr_h.T + br_h + br_f
// ---------------------------------------------------------------------------
__global__ __launch_bounds__(256) void k_hproj(
    const float* __restrict__ hidden,
    const float* __restrict__ Wsh, const float* __restrict__ bsh,
    const float* __restrict__ bsf,
    const float* __restrict__ Wrh, const float* __restrict__ brh,
    const float* __restrict__ brf,
    float* __restrict__ hs, float* __restrict__ hr)
{
    __shared__ float hid[H_SZ];
    const int b = blockIdx.x, t = threadIdx.x;
    for (int i = t; i < H_SZ; i += 256) hid[i] = hidden[b * H_SZ + i];
    __syncthreads();
    for (int h = t; h < H_SZ; h += 256) {
        float a1 = bsh[h] + bsf[h];
        float a2 = brh[h] + brf[h];
        const float* r1 = Wsh + (size_t)h * H_SZ;
        const float* r2 = Wrh + (size_t)h * H_SZ;
        for (int k = 0; k < H_SZ; k += 4) {
            float4 v1 = *(const float4*)(r1 + k);
            float4 v2 = *(const float4*)(r2 + k);
            a1 += hid[k] * v1.x + hid[k+1] * v1.y + hid[k+2] * v1.z + hid[k+3] * v1.w;
            a2 += hid[k] * v2.x + hid[k+1] * v2.y + hid[k+2] * v2.z + hid[k+3] * v2.w;
        }
        hs[b * H_SZ + h] = a1;
        hr[b * H_SZ + h] = a2;
    }
}

// ---------------------------------------------------------------------------
// e1[m] = sum_h tanh( feats[m,:]@Wsf[h,:] + hs[b(m),h] ) * was[h]
// MFMA bf16: A = 64 rows x full K=512 in LDS (XOR-swizzled, staged once);
// B frags read straight from L2-resident bf16 Wsb. Zero barriers in main loop.
// ---------------------------------------------------------------------------
__global__ __launch_bounds__(256) void k_e1_mfma(
    const float* __restrict__ feats,        // (46080, 512) fp32
    const unsigned short* __restrict__ Wsb, // (512, 512) bf16
    const float* __restrict__ was,
    const float* __restrict__ hs,
    float* __restrict__ e1)
{
    __shared__ __align__(16) unsigned char As[64 * 1024];  // 64 rows x 512 k bf16, swizzled
    __shared__ float hsl[2 * H_SZ];
    __shared__ float wasl[H_SZ];
    __shared__ float eps[2][64];

    const int t = threadIdx.x;
    const int m0 = blockIdx.x * 64;
    const int b0 = m0 / FNB, b1 = (m0 + 63) / FNB;

    for (int i = t; i < H_SZ; i += 256) {
        hsl[i]        = hs[b0 * H_SZ + i];
        hsl[H_SZ + i] = hs[b1 * H_SZ + i];
        wasl[i]       = was[i];
    }
    // Stage A: fp32 -> bf16, swizzle byte ^= (row&7)<<4 within each 1024B row
#pragma unroll 4
    for (int it = 0; it < 16; it++) {
        int idx = it * 256 + t;
        int r = idx >> 6, c = idx & 63;               // chunk = 8 elems = 16B
        const float* src = feats + (size_t)(m0 + r) * R_SZ + c * 8;
        float4 f0 = *(const float4*)src;
        float4 f1 = *(const float4*)(src + 4);
        *(short8*)(As + r * 1024 + ((c * 16) ^ ((r & 7) << 4))) = cvt8(f0, f1);
    }
    __syncthreads();

    const int lane = t & 63;
    const int w = t >> 6;
    const int wr = w >> 1, wc = w & 1;                // wave = 2x2 grid of 32x32 tiles
    const int l15 = lane & 15, lk = lane >> 4;
    const int thr = (b0 + 1) * FNB - m0;              // rows >= thr belong to b1

    const int r0 = wr * 32 + l15;
    const int abase0 = r0 * 1024,        xr0 = (r0 & 7) << 4;
    const int abase1 = (r0 + 16) * 1024, xr1 = ((r0 + 16) & 7) << 4;

    float ep[2][4] = {{0.f,0.f,0.f,0.f},{0.f,0.f,0.f,0.f}};

    for (int h0 = 0; h0 < H_SZ; h0 += 64) {
        f32x4 acc[2][2] = {};
        const unsigned short* bp0 = Wsb + (size_t)(h0 + wc * 32 + l15) * 512 + lk * 8;
        const unsigned short* bp1 = bp0 + 16 * 512;
#pragma unroll
        for (int ks = 0; ks < 16; ks++) {
            short8 a[2], bv[2];
            a[0]  = *(const short8*)(As + abase0 + ((ks * 64 + lk * 16) ^ xr0));
            a[1]  = *(const short8*)(As + abase1 + ((ks * 64 + lk * 16) ^ xr1));
            bv[0] = *(const short8*)(bp0 + ks * 32);
            bv[1] = *(const short8*)(bp1 + ks * 32);
#pragma unroll
            for (int fr = 0; fr < 2; fr++)
#pragma unroll
                for (int fc = 0; fc < 2; fc++)
                    acc[fr][fc] = __builtin_amdgcn_mfma_f32_16x16x32_bf16(
                        a[fr], bv[fc], acc[fr][fc], 0, 0, 0);
        }
        // epilogue: ep[row] += tanh(acc + hs[b(row), h]) * was[h]
#pragma unroll
        for (int fc = 0; fc < 2; fc++) {
            int h = h0 + wc * 32 + fc * 16 + l15;
            float wv = wasl[h];
#pragma unroll
            for (int fr = 0; fr < 2; fr++) {
#pragma unroll
                for (int q = 0; q < 4; q++) {
                    int r = wr * 32 + fr * 16 + lk * 4 + q;   // C/D: col=lane&15, row=(lane>>4)*4+q
                    float hv = hsl[(r >= thr ? H_SZ : 0) + h];
                    ep[fr][q] += fast_tanh(acc[fr][fc][q] + hv) * wv;
                }
            }
        }
    }
    // reduce over 16 columns per lane-group, then over the two wave-column halves
#pragma unroll
    for (int fr = 0; fr < 2; fr++)
#pragma unroll
        for (int q = 0; q < 4; q++) {
            float v = ep[fr][q];
            v += __shfl_xor(v, 1);
            v += __shfl_xor(v, 2);
            v += __shfl_xor(v, 4);
            v += __shfl_xor(v, 8);
            if (l15 == 0) eps[wc][wr * 32 + fr * 16 + lk * 4 + q] = v;
        }
    __syncthreads();
    if (t < 64) e1[m0 + t] = eps[0][t] + eps[1][t];
}

// ---------------------------------------------------------------------------
// per n: softmax over 36 e1's, att = alpha-weighted sum of feats rows,
// feat[n] = [att(512) | i3d(1024)] bf16 (internal staging format)
// ---------------------------------------------------------------------------
__global__ __launch_bounds__(256) void k_softatt(
    const float* __restrict__ feats,
    const float* __restrict__ i3d,
    const float* __restrict__ e1,
    unsigned short* __restrict__ feat)
{
    __shared__ float alpha[NB_SZ];
    const int n = blockIdx.x, t = threadIdx.x;
    if (t < 64) {
        float v = (t < NB_SZ) ? e1[n * NB_SZ + t] : -1e30f;
        float m = v;
#pragma unroll
        for (int off = 32; off; off >>= 1) m = fmaxf(m, __shfl_xor(m, off));
        float ex = (t < NB_SZ) ? expf(v - m) : 0.f;
        float ssum = ex;
#pragma unroll
        for (int off = 32; off; off >>= 1) ssum += __shfl_xor(ssum, off);
        if (t < NB_SZ) alpha[t] = ex / ssum;
    }
    __syncthreads();

    float a0 = 0.f, a1 = 0.f;
    const float* base = feats + (size_t)n * NB_SZ * R_SZ;
    for (int ll = 0; ll < NB_SZ; ll++) {
        float al = alpha[ll];
        float2 pv = *(const float2*)(base + ll * R_SZ + 2 * t);
        a0 += al * pv.x;
        a1 += al * pv.y;
    }
    feat[(size_t)n * D_SZ + 2 * t]     = f2bf(a0);
    feat[(size_t)n * D_SZ + 2 * t + 1] = f2bf(a1);
    float4 iv = *(const float4*)(i3d + (size_t)n * 1024 + t * 4);
    unsigned short o[4] = {f2bf(iv.x), f2bf(iv.y), f2bf(iv.z), f2bf(iv.w)};
    *(uint2*)(feat + (size_t)n * D_SZ + 512 + t * 4) = *(const uint2*)o;
}

// ---------------------------------------------------------------------------
// p[n, j] = feat[n,:] @ Wr_f-row(j); j<512 -> Wr1 row j, j>=512 -> Wr2 row j-512
// MFMA bf16: A = feat tile (already bf16) staged+swizzled in LDS (BK=512);
// B frags loaded fp32 from Wrf and converted inline.
// ---------------------------------------------------------------------------
__global__ __launch_bounds__(256) void k_pgemm_mfma(
    const unsigned short* __restrict__ feat,  // (1280, 1536) bf16
    const float* __restrict__ Wrf,            // (512, 3072) fp32
    float* __restrict__ p)                    // (1280, 1024) fp32
{
    __shared__ __align__(16) unsigned char As[64 * 1024];  // 64 rows x 512 k bf16, swizzled
    const int t = threadIdx.x;
    const int m0 = blockIdx.x * 64;
    const int j0 = blockIdx.y * 64;
    const int jb   = (j0 >= 512) ? (j0 - 512) : j0;
    const int coff = (j0 >= 512) ? D_SZ : 0;

    const int lane = t & 63, w = t >> 6;
    const int wr = w >> 1, wc = w & 1;
    const int l15 = lane & 15, lk = lane >> 4;

    const int r0 = wr * 32 + l15;
    const int abase0 = r0 * 1024,        xr0 = (r0 & 7) << 4;
    const int abase1 = (r0 + 16) * 1024, xr1 = ((r0 + 16) & 7) << 4;

    f32x4 acc[2][2] = {};
    const float* bsrc0 = Wrf + (size_t)(jb + wc * 32 + l15) * 3072 + coff + lk * 8;
    const float* bsrc1 = bsrc0 + (size_t)16 * 3072;

    for (int k0 = 0; k0 < D_SZ; k0 += 512) {
        __syncthreads();
#pragma unroll 4
        for (int it = 0; it < 16; it++) {
            int idx = it * 256 + t;
            int r = idx >> 6, c = idx & 63;
            int4 v = *(const int4*)(feat + (size_t)(m0 + r) * D_SZ + k0 + c * 8);
            *(int4*)(As + r * 1024 + ((c * 16) ^ ((r & 7) << 4))) = v;
        }
        __syncthreads();
#pragma unroll 4
        for (int ks = 0; ks < 16; ks++) {
            short8 a[2], bv[2];
            a[0] = *(const short8*)(As + abase0 + ((ks * 64 + lk * 16) ^ xr0));
            a[1] = *(const short8*)(As + abase1 + ((ks * 64 + lk * 16) ^ xr1));
#pragma unroll
            for (int fc = 0; fc < 2; fc++) {
                const float* bs = (fc ? bsrc1 : bsrc0) + k0 + ks * 32;
                float4 f0 = *(const float4*)bs;
                float4 f1 = *(const float4*)(bs + 4);
                bv[fc] = cvt8(f0, f1);
            }
#pragma unroll
            for (int fr = 0; fr < 2; fr++)
#pragma unroll
                for (int fc = 0; fc < 2; fc++)
                    acc[fr][fc] = __builtin_amdgcn_mfma_f32_16x16x32_bf16(
                        a[fr], bv[fc], acc[fr][fc], 0, 0, 0);
        }
    }
#pragma unroll
    for (int fr = 0; fr < 2; fr++)
#pragma unroll
        for (int fc = 0; fc < 2; fc++)
#pragma unroll
            for (int q = 0; q < 4; q++) {
                int row = m0 + wr * 32 + fr * 16 + lk * 4 + q;
                int col = j0 + wc * 32 + fc * 16 + l15;
                p[(size_t)row * 1024 + col] = acc[fr][fc][q];
            }
}

// ---------------------------------------------------------------------------
// e2[b,i,j] = sum_d tanh(p2[b*F+i,d] + p1[b*F+j,d] + hr[b,d]) * war[d]
// ---------------------------------------------------------------------------
__global__ __launch_bounds__(256) void k_e2(
    const float* __restrict__ p,
    const float* __restrict__ hr,
    const float* __restrict__ war,
    float* __restrict__ e2)
{
    const int blk = blockIdx.x;
    const int b = blk / F_SZ, i = blk % F_SZ;
    const int t = threadIdx.x;
    const int w = t >> 6, l = t & 63;
    const int ni = b * F_SZ + i;

    float base[8], warf[8];
    {
        float4 pa = *(const float4*)(p + (size_t)ni * 1024 + 512 + l * 8);
        float4 pb = *(const float4*)(p + (size_t)ni * 1024 + 512 + l * 8 + 4);
        float4 ha = *(const float4*)(hr + b * H_SZ + l * 8);
        float4 hb = *(const float4*)(hr + b * H_SZ + l * 8 + 4);
        base[0] = pa.x + ha.x; base[1] = pa.y + ha.y; base[2] = pa.z + ha.z; base[3] = pa.w + ha.w;
        base[4] = pb.x + hb.x; base[5] = pb.y + hb.y; base[6] = pb.z + hb.z; base[7] = pb.w + hb.w;
        float4 wa = *(const float4*)(war + l * 8);
        float4 wb = *(const float4*)(war + l * 8 + 4);
        warf[0] = wa.x; warf[1] = wa.y; warf[2] = wa.z; warf[3] = wa.w;
        warf[4] = wb.x; warf[5] = wb.y; warf[6] = wb.z; warf[7] = wb.w;
    }

    for (int j = w; j < F_SZ; j += 4) {
        const float* p1r = p + (size_t)(b * F_SZ + j) * 1024;
        float4 va = *(const float4*)(p1r + l * 8);
        float4 vb = *(const float4*)(p1r + l * 8 + 4);
        float pv[8] = {va.x, va.y, va.z, va.w, vb.x, vb.y, vb.z, vb.w};
        float s = 0.f;
#pragma unroll
        for (int u = 0; u < 8; u++) s += fast_tanh(pv[u] + base[u]) * warf[u];
#pragma unroll
        for (int off = 32; off; off >>= 1) s += __shfl_xor(s, off);
        if (l == 0) e2[(size_t)b * 1600 + i * F_SZ + j] = s;
    }
}

// ---------------------------------------------------------------------------
// per b: softmax over 1600 e2's, rowsum/colsum, then
// out[b] = [ sum_j colsum_j*feat[b,j,:] | sum_i rowsum_i*feat[b,i,:] ]  (FP32 OUT)
// ---------------------------------------------------------------------------
__global__ __launch_bounds__(256) void k_out(
    const float* __restrict__ e2,
    const unsigned short* __restrict__ feat,
    float* __restrict__ out)                   // (32, 3072) FP32
{
    __shared__ float alpha[1600];
    __shared__ float red[4];
    __shared__ float rs[F_SZ], cs[F_SZ];
    const int b = blockIdx.x, t = threadIdx.x;
    const int w = t >> 6, l = t & 63;

    float lm = -1e30f;
    for (int idx = t; idx < 1600; idx += 256) {
        float v = e2[(size_t)b * 1600 + idx];
        alpha[idx] = v;
        lm = fmaxf(lm, v);
    }
#pragma unroll
    for (int off = 32; off; off >>= 1) lm = fmaxf(lm, __shfl_xor(lm, off));
    if (l == 0) red[w] = lm;
    __syncthreads();
    float M = fmaxf(fmaxf(red[0], red[1]), fmaxf(red[2], red[3]));
    __syncthreads();
    float ls = 0.f;
    for (int idx = t; idx < 1600; idx += 256) {
        float ex = expf(alpha[idx] - M);
        alpha[idx] = ex;
        ls += ex;
    }
#pragma unroll
    for (int off = 32; off; off >>= 1) ls += __shfl_xor(ls, off);
    if (l == 0) red[w] = ls;
    __syncthreads();
    float inv = 1.f / (red[0] + red[1] + red[2] + red[3]);

    if (t < F_SZ) {
        float s = 0.f;
        for (int j = 0; j < F_SZ; j++) s += alpha[t * F_SZ + j];
        rs[t] = s * inv;
    } else if (t >= 128 && t < 128 + F_SZ) {
        int j = t - 128;
        float s = 0.f;
        for (int i2 = 0; i2 < F_SZ; i2++) s += alpha[i2 * F_SZ + j];
        cs[j] = s * inv;
    }
    __syncthreads();

    float a1[6] = {0.f,0.f,0.f,0.f,0.f,0.f};
    float a2[6] = {0.f,0.f,0.f,0.f,0.f,0.f};
    for (int r = 0; r < F_SZ; r++) {
        float w1 = cs[r], w2 = rs[r];
        const unsigned short* fr = feat + (size_t)(b * F_SZ + r) * D_SZ;
#pragma unroll
        for (int u = 0; u < 6; u++) {
            float f = bf2f(fr[t + u * 256]);
            a1[u] += w1 * f;
            a2[u] += w2 * f;
        }
    }
#pragma unroll
    for (int u = 0; u < 6; u++) {
        out[(size_t)b * 3072 + t + u * 256]        = a1[u];
        out[(size_t)b * 3072 + 1536 + t + u * 256] = a2[u];
    }
}

// ---------------------------------------------------------------------------
extern "C" void kernel_launch(void* const* d_in, const int* in_sizes, int n_in,
                              void* d_out, int out_size, void* d_ws, size_t ws_size,
                              hipStream_t stream) {
    const float* i3d    = (const float*)d_in[0];
    const float* objf   = (const float*)d_in[1];
    const float* hidden = (const float*)d_in[2];
    const float* Wsf    = (const float*)d_in[3];
    const float* bsf    = (const float*)d_in[4];
    const float* Wsh    = (const float*)d_in[5];
    const float* bsh    = (const float*)d_in[6];
    const float* was    = (const float*)d_in[7];
    const float* Wrf    = (const float*)d_in[8];
    const float* brf    = (const float*)d_in[9];
    const float* Wrh    = (const float*)d_in[10];
    const float* brh    = (const float*)d_in[11];
    const float* war    = (const float*)d_in[12];
    float* out = (float*)d_out;

    char* ws = (char*)d_ws;
    float* hs = (float*)(ws);
    float* hr = (float*)(ws + 65536);
    float* e1 = (float*)(ws + 131072);
    float* e2 = (float*)(ws + 315392);
    float* p  = (float*)(ws + 520192);
    unsigned short* feat = (unsigned short*)(ws + 5763072);
    // Wsb lives in the TAIL of the p region: consumed by k_e1_mfma, which runs
    // strictly before k_pgemm_mfma writes p. Total ws footprint unchanged.
    unsigned short* Wsb = (unsigned short*)(ws + 5238784);  // 512 KB, 16B aligned

    k_cast<<<dim3(128), dim3(256), 0, stream>>>(Wsf, Wsb);
    k_hproj<<<dim3(B_SZ), dim3(256), 0, stream>>>(hidden, Wsh, bsh, bsf, Wrh, brh, brf, hs, hr);
    k_e1_mfma<<<dim3(M1 / 64), dim3(256), 0, stream>>>(objf, Wsb, was, hs, e1);
    k_softatt<<<dim3(NROW), dim3(256), 0, stream>>>(objf, i3d, e1, feat);
    k_pgemm_mfma<<<dim3(NROW / 64, 1024 / 64), dim3(256), 0, stream>>>(feat, Wrf, p);
    k_e2<<<dim3(NROW), dim3(256), 0, stream>>>(p, hr, war, e2);
    k_out<<<dim3(B_SZ), dim3(256), 0, stream>>>(e2, feat, out);
}

// Round 2
// 327.537 us; speedup vs baseline: 1.2929x; 1.2929x over previous
//
#include <hip/hip_runtime.h>
#include <stdint.h>

// Problem constants
#define B_SZ 32
#define F_SZ 40
#define NB_SZ 36
#define R_SZ 512
#define H_SZ 512
#define D_SZ 1536
#define M1 (B_SZ * F_SZ * NB_SZ)   // 46080
#define NROW (B_SZ * F_SZ)         // 1280
#define FNB (F_SZ * NB_SZ)         // 1440

typedef __attribute__((ext_vector_type(8))) short short8;   // 8 bf16 (MFMA A/B frag)
typedef __attribute__((ext_vector_type(4))) float f32x4;    // MFMA C/D frag

__device__ __forceinline__ unsigned short f2bf(float f) {
    unsigned int x = __float_as_uint(f);
    return (unsigned short)((x + 0x7fffu + ((x >> 16) & 1u)) >> 16);  // RNE
}
__device__ __forceinline__ float bf2f(unsigned short u) {
    union { unsigned int i; float f; } v; v.i = ((unsigned int)u) << 16; return v.f;
}
__device__ __forceinline__ unsigned int cvtpk(float lo, float hi) {
    unsigned int r;
    asm("v_cvt_pk_bf16_f32 %0, %1, %2" : "=v"(r) : "v"(lo), "v"(hi));
    return r;
}
__device__ __forceinline__ float fast_rcp(float x) {
    float r; asm("v_rcp_f32 %0, %1" : "=v"(r) : "v"(x)); return r;
}
__device__ __forceinline__ float fast_tanh(float x) {
    float cx = fminf(fmaxf(x, -9.0f), 9.0f);
    float e = __expf(2.0f * cx);
    return (e - 1.0f) * fast_rcp(e + 1.0f);
}

// ---------------------------------------------------------------------------
// Wsb = bf16(Wsf)  (512x512)
// ---------------------------------------------------------------------------
__global__ __launch_bounds__(256) void k_cast(
    const float* __restrict__ Wsf, unsigned short* __restrict__ Wsb)
{
    int i = (blockIdx.x * 256 + threadIdx.x) * 8;
    float4 f0 = *(const float4*)(Wsf + i);
    float4 f1 = *(const float4*)(Wsf + i + 4);
    unsigned int u0 = cvtpk(f0.x, f0.y), u1 = cvtpk(f0.z, f0.w);
    unsigned int u2 = cvtpk(f1.x, f1.y), u3 = cvtpk(f1.z, f1.w);
    uint4 pk = {u0, u1, u2, u3};
    *(uint4*)(Wsb + i) = pk;
}

// ---------------------------------------------------------------------------
// hs[b,h] = hidden[b]@Ws_h.T + bs_h + bs_f ; hr[b,h] = hidden[b]@Wr_h.T + br_h + br_f
// grid = 32 b x 8 h-chunks = 256 blocks; 4 threads per h (quarter-K each)
// ---------------------------------------------------------------------------
__global__ __launch_bounds__(256) void k_hproj(
    const float* __restrict__ hidden,
    const float* __restrict__ Wsh, const float* __restrict__ bsh,
    const float* __restrict__ bsf,
    const float* __restrict__ Wrh, const float* __restrict__ brh,
    const float* __restrict__ brf,
    float* __restrict__ hs, float* __restrict__ hr)
{
    __shared__ float hid[H_SZ];
    const int b = blockIdx.x >> 3, hc = blockIdx.x & 7;
    const int t = threadIdx.x;
    for (int i = t; i < H_SZ; i += 256) hid[i] = hidden[b * H_SZ + i];
    __syncthreads();
    const int h = hc * 64 + (t >> 2), kq = t & 3;
    const float* r1 = Wsh + (size_t)h * H_SZ + kq * 128;
    const float* r2 = Wrh + (size_t)h * H_SZ + kq * 128;
    const float* hh = hid + kq * 128;
    float a1 = 0.f, a2 = 0.f;
    for (int k = 0; k < 128; k += 4) {
        float4 v1 = *(const float4*)(r1 + k);
        float4 v2 = *(const float4*)(r2 + k);
        a1 += hh[k] * v1.x + hh[k+1] * v1.y + hh[k+2] * v1.z + hh[k+3] * v1.w;
        a2 += hh[k] * v2.x + hh[k+1] * v2.y + hh[k+2] * v2.z + hh[k+3] * v2.w;
    }
    a1 += __shfl_xor(a1, 1); a1 += __shfl_xor(a1, 2);
    a2 += __shfl_xor(a2, 1); a2 += __shfl_xor(a2, 2);
    if (kq == 0) {
        hs[b * H_SZ + h] = a1 + bsh[h] + bsf[h];
        hr[b * H_SZ + h] = a2 + brh[h] + brf[h];
    }
}

// ---------------------------------------------------------------------------
// e1 partials: block = 128 m-rows x 128 h-cols, BK=64, 4 waves in 2x2.
// e1p[by][m] = sum_{h in by-tile} tanh(S[m,h] + hs[b(m),h]) * was[h]
// A: fp32->bf16 reg-staged to LDS; B: bf16 int4-staged. XOR swizzle c^(r&7).
// ---------------------------------------------------------------------------
__global__ __launch_bounds__(256) void k_e1_mfma(
    const float* __restrict__ feats,        // (46080, 512) fp32
    const unsigned short* __restrict__ Wsb, // (512, 512) bf16
    const float* __restrict__ was,
    const float* __restrict__ hs,
    float* __restrict__ e1p)                // (4, 46080) fp32
{
    __shared__ __align__(16) unsigned char As[128 * 128];  // 128 rows x 64 k bf16
    __shared__ __align__(16) unsigned char Bs[128 * 128];  // 128 hrows x 64 k bf16
    __shared__ float hsl[2 * 128];
    __shared__ float wasl[128];
    __shared__ float eps[2][128];

    // bijective XCD swizzle: 1440 = 8 * 180; 4 by-siblings adjacent on one XCD
    const int bx = blockIdx.x;
    const int wid = (bx & 7) * 180 + (bx >> 3);
    const int mb = wid >> 2, by = wid & 3;
    const int m0 = mb * 128, hb = by * 128;
    const int t = threadIdx.x;
    const int b0 = m0 / FNB, b1 = (m0 + 127) / FNB;
    const int thr = (b0 + 1) * FNB - m0;   // local rows >= thr belong to b1

    if (t < 128) {
        hsl[t]       = hs[b0 * H_SZ + hb + t];
        hsl[128 + t] = hs[b1 * H_SZ + hb + t];
        wasl[t]      = was[hb + t];
    }

    const int lane = t & 63, w = t >> 6;
    const int wr = w >> 1, wc = w & 1;            // wave 2x2 over (m,h)
    const int l15 = lane & 15, lk = lane >> 4;

    // per-thread fragment base offsets (row part + XOR term), constant over k0
    int aoff[4], boff[4];
#pragma unroll
    for (int i = 0; i < 4; i++) {
        int ra = wr * 64 + i * 16 + l15;
        aoff[i] = ra * 128 + (((lk) ^ (ra & 7)) << 4);   // ks adds (ks*4)<<4 via XOR-free add? no: use XOR form below
        int rb = wc * 64 + i * 16 + l15;
        boff[i] = rb * 128 + (((lk) ^ (rb & 7)) << 4);
    }
    // NOTE: c = ks*4 + lk; (c ^ (r&7))<<4 = ((lk ^ (r&7))<<4) ^ (ks<<6) since ks*4
    // toggles bit 2 of c only when lk<4 and r&7<4... NOT generally XOR-separable.
    // Recompute safely per use instead:
    int ar[4], br_[4];
#pragma unroll
    for (int i = 0; i < 4; i++) {
        ar[i]  = wr * 64 + i * 16 + l15;
        br_[i] = wc * 64 + i * 16 + l15;
    }

    float ep[4][4] = {{0.f}};
    f32x4 acc[4][4] = {};

    for (int k0 = 0; k0 < R_SZ; k0 += 64) {
        // --- issue global loads into regs (overlaps with prior MFMA drain) ---
        float4 alo[4], ahi[4];
        int4 bfr[4];
#pragma unroll
        for (int i = 0; i < 4; i++) {
            int cid = i * 256 + t;                 // 1024 chunks of 8 elems
            int r = cid >> 3, c = cid & 7;
            const float* src = feats + (size_t)(m0 + r) * R_SZ + k0 + c * 8;
            alo[i] = *(const float4*)src;
            ahi[i] = *(const float4*)(src + 4);
            bfr[i] = *(const int4*)(Wsb + (size_t)(hb + r) * R_SZ + k0 + c * 8);
        }
        __syncthreads();   // prev compute done (iter0: hsl staged)
#pragma unroll
        for (int i = 0; i < 4; i++) {
            int cid = i * 256 + t;
            int r = cid >> 3, c = cid & 7;
            unsigned int u0 = cvtpk(alo[i].x, alo[i].y), u1 = cvtpk(alo[i].z, alo[i].w);
            unsigned int u2 = cvtpk(ahi[i].x, ahi[i].y), u3 = cvtpk(ahi[i].z, ahi[i].w);
            uint4 pk = {u0, u1, u2, u3};
            int sw = (c ^ (r & 7)) << 4;
            *(uint4*)(As + r * 128 + sw) = pk;
            *(int4*)(Bs + r * 128 + sw) = bfr[i];
        }
        __syncthreads();
        // --- compute: 2 ks x 32 MFMA per wave ---
#pragma unroll
        for (int ks = 0; ks < 2; ks++) {
            short8 a[4], b[4];
#pragma unroll
            for (int i = 0; i < 4; i++) {
                int c = ks * 4 + lk;
                a[i] = *(const short8*)(As + ar[i] * 128 + ((c ^ (ar[i] & 7)) << 4));
                b[i] = *(const short8*)(Bs + br_[i] * 128 + ((c ^ (br_[i] & 7)) << 4));
            }
#pragma unroll
            for (int i = 0; i < 4; i++)
#pragma unroll
                for (int j = 0; j < 4; j++)
                    acc[i][j] = __builtin_amdgcn_mfma_f32_16x16x32_bf16(
                        a[i], b[j], acc[i][j], 0, 0, 0);
        }
    }

    // --- epilogue: tanh + was-weighted row partials ---
#pragma unroll
    for (int j = 0; j < 4; j++) {
        int hl = wc * 64 + j * 16 + l15;
        float wv = wasl[hl];
#pragma unroll
        for (int i = 0; i < 4; i++) {
#pragma unroll
            for (int q = 0; q < 4; q++) {
                int r = wr * 64 + i * 16 + lk * 4 + q;
                float hv = hsl[(r >= thr ? 128 : 0) + hl];
                ep[i][q] += fast_tanh(acc[i][j][q] + hv) * wv;
            }
        }
    }
#pragma unroll
    for (int i = 0; i < 4; i++)
#pragma unroll
        for (int q = 0; q < 4; q++) {
            float v = ep[i][q];
            v += __shfl_xor(v, 1);
            v += __shfl_xor(v, 2);
            v += __shfl_xor(v, 4);
            v += __shfl_xor(v, 8);
            if (l15 == 0) eps[wc][wr * 64 + i * 16 + lk * 4 + q] = v;
        }
    __syncthreads();
    if (t < 128) e1p[(size_t)by * M1 + m0 + t] = eps[0][t] + eps[1][t];
}

// ---------------------------------------------------------------------------
// per n: softmax over 36 e1's (sum of 4 partials), att = alpha-weighted sum,
// feat[n] = [att(512) | i3d(1024)] bf16
// ---------------------------------------------------------------------------
__global__ __launch_bounds__(256) void k_softatt(
    const float* __restrict__ feats,
    const float* __restrict__ i3d,
    const float* __restrict__ e1p,
    unsigned short* __restrict__ feat)
{
    __shared__ float alpha[NB_SZ];
    const int n = blockIdx.x, t = threadIdx.x;
    if (t < 64) {
        float v = -1e30f;
        if (t < NB_SZ) {
            int idx = n * NB_SZ + t;
            v = e1p[idx] + e1p[M1 + idx] + e1p[2 * M1 + idx] + e1p[3 * M1 + idx];
        }
        float m = v;
#pragma unroll
        for (int off = 32; off; off >>= 1) m = fmaxf(m, __shfl_xor(m, off));
        float ex = (t < NB_SZ) ? expf(v - m) : 0.f;
        float ssum = ex;
#pragma unroll
        for (int off = 32; off; off >>= 1) ssum += __shfl_xor(ssum, off);
        if (t < NB_SZ) alpha[t] = ex / ssum;
    }
    __syncthreads();

    float a0 = 0.f, a1 = 0.f;
    const float* base = feats + (size_t)n * NB_SZ * R_SZ;
    for (int ll = 0; ll < NB_SZ; ll++) {
        float al = alpha[ll];
        float2 pv = *(const float2*)(base + ll * R_SZ + 2 * t);
        a0 += al * pv.x;
        a1 += al * pv.y;
    }
    feat[(size_t)n * D_SZ + 2 * t]     = f2bf(a0);
    feat[(size_t)n * D_SZ + 2 * t + 1] = f2bf(a1);
    float4 iv = *(const float4*)(i3d + (size_t)n * 1024 + t * 4);
    unsigned short o[4] = {f2bf(iv.x), f2bf(iv.y), f2bf(iv.z), f2bf(iv.w)};
    *(uint2*)(feat + (size_t)n * D_SZ + 512 + t * 4) = *(const uint2*)o;
}

// ---------------------------------------------------------------------------
// p[n, j] = feat[n,:] @ Wr_f-row(j); tile 64m x 64n, BK=128, 4 waves 2x2.
// A: feat bf16 int4-staged; B: Wrf fp32 reg-staged->bf16. XOR swizzle.
// ---------------------------------------------------------------------------
__global__ __launch_bounds__(256) void k_pgemm_mfma(
    const unsigned short* __restrict__ feat,  // (1280, 1536) bf16
    const float* __restrict__ Wrf,            // (512, 3072) fp32
    float* __restrict__ p)                    // (1280, 1024) fp32
{
    __shared__ __align__(16) unsigned char As[64 * 256];  // 64 rows x 128 k bf16
    __shared__ __align__(16) unsigned char Bs[64 * 256];  // 64 jrows x 128 k bf16

    // bijective XCD swizzle: 320 = 8 * 40; n-major within XCD for Wrf reuse
    const int bx = blockIdx.x;
    const int wid = (bx & 7) * 40 + (bx >> 3);
    const int mb = wid % 20, nb = wid / 20;
    const int m0 = mb * 64, j0 = nb * 64;
    const int t = threadIdx.x;

    const int lane = t & 63, w = t >> 6;
    const int wr = w >> 1, wc = w & 1;
    const int l15 = lane & 15, lk = lane >> 4;

    int ar[2], br_[2];
#pragma unroll
    for (int i = 0; i < 2; i++) {
        ar[i]  = wr * 32 + i * 16 + l15;
        br_[i] = wc * 32 + i * 16 + l15;
    }

    // B source row base (uniform branch: 64-tile never straddles 512)
    const size_t brow_base = (j0 < 512) ? (size_t)j0 * 3072 : ((size_t)(j0 - 512) * 3072 + 1536);

    f32x4 acc[2][2] = {};

    for (int k0 = 0; k0 < D_SZ; k0 += 128) {
        // A: 64 rows x 16 chunks of 8 bf16 = 1024 chunks
        int4 afr[4];
        float4 blo[4], bhi[4];
#pragma unroll
        for (int i = 0; i < 4; i++) {
            int cid = i * 256 + t;
            int r = cid >> 4, c = cid & 15;
            afr[i] = *(const int4*)(feat + (size_t)(m0 + r) * D_SZ + k0 + c * 8);
            const float* bs = Wrf + brow_base + (size_t)r * 3072 + k0 + c * 8;
            blo[i] = *(const float4*)bs;
            bhi[i] = *(const float4*)(bs + 4);
        }
        __syncthreads();
#pragma unroll
        for (int i = 0; i < 4; i++) {
            int cid = i * 256 + t;
            int r = cid >> 4, c = cid & 15;
            int sw = (c ^ (r & 7)) << 4;
            *(int4*)(As + r * 256 + sw) = afr[i];
            unsigned int u0 = cvtpk(blo[i].x, blo[i].y), u1 = cvtpk(blo[i].z, blo[i].w);
            unsigned int u2 = cvtpk(bhi[i].x, bhi[i].y), u3 = cvtpk(bhi[i].z, bhi[i].w);
            uint4 pk = {u0, u1, u2, u3};
            *(uint4*)(Bs + r * 256 + sw) = pk;
        }
        __syncthreads();
#pragma unroll
        for (int ks = 0; ks < 4; ks++) {
            short8 a[2], b[2];
            int c = ks * 4 + lk;
#pragma unroll
            for (int i = 0; i < 2; i++) {
                a[i] = *(const short8*)(As + ar[i] * 256 + ((c ^ (ar[i] & 7)) << 4));
                b[i] = *(const short8*)(Bs + br_[i] * 256 + ((c ^ (br_[i] & 7)) << 4));
            }
#pragma unroll
            for (int i = 0; i < 2; i++)
#pragma unroll
                for (int j = 0; j < 2; j++)
                    acc[i][j] = __builtin_amdgcn_mfma_f32_16x16x32_bf16(
                        a[i], b[j], acc[i][j], 0, 0, 0);
        }
    }
#pragma unroll
    for (int i = 0; i < 2; i++)
#pragma unroll
        for (int j = 0; j < 2; j++)
#pragma unroll
            for (int q = 0; q < 4; q++) {
                int row = m0 + wr * 32 + i * 16 + lk * 4 + q;
                int col = j0 + wc * 32 + j * 16 + l15;
                p[(size_t)row * 1024 + col] = acc[i][j][q];
            }
}

// ---------------------------------------------------------------------------
// e2[b,i,j] = sum_d tanh(p2[b*F+i,d] + p1[b*F+j,d] + hr[b,d]) * war[d]
// ---------------------------------------------------------------------------
__global__ __launch_bounds__(256) void k_e2(
    const float* __restrict__ p,
    const float* __restrict__ hr,
    const float* __restrict__ war,
    float* __restrict__ e2)
{
    const int blk = blockIdx.x;
    const int b = blk / F_SZ, i = blk % F_SZ;
    const int t = threadIdx.x;
    const int w = t >> 6, l = t & 63;
    const int ni = b * F_SZ + i;

    float base[8], warf[8];
    {
        float4 pa = *(const float4*)(p + (size_t)ni * 1024 + 512 + l * 8);
        float4 pb = *(const float4*)(p + (size_t)ni * 1024 + 512 + l * 8 + 4);
        float4 ha = *(const float4*)(hr + b * H_SZ + l * 8);
        float4 hb = *(const float4*)(hr + b * H_SZ + l * 8 + 4);
        base[0] = pa.x + ha.x; base[1] = pa.y + ha.y; base[2] = pa.z + ha.z; base[3] = pa.w + ha.w;
        base[4] = pb.x + hb.x; base[5] = pb.y + hb.y; base[6] = pb.z + hb.z; base[7] = pb.w + hb.w;
        float4 wa = *(const float4*)(war + l * 8);
        float4 wb = *(const float4*)(war + l * 8 + 4);
        warf[0] = wa.x; warf[1] = wa.y; warf[2] = wa.z; warf[3] = wa.w;
        warf[4] = wb.x; warf[5] = wb.y; warf[6] = wb.z; warf[7] = wb.w;
    }

    for (int j = w; j < F_SZ; j += 4) {
        const float* p1r = p + (size_t)(b * F_SZ + j) * 1024;
        float4 va = *(const float4*)(p1r + l * 8);
        float4 vb = *(const float4*)(p1r + l * 8 + 4);
        float pv[8] = {va.x, va.y, va.z, va.w, vb.x, vb.y, vb.z, vb.w};
        float s = 0.f;
#pragma unroll
        for (int u = 0; u < 8; u++) s += fast_tanh(pv[u] + base[u]) * warf[u];
#pragma unroll
        for (int off = 32; off; off >>= 1) s += __shfl_xor(s, off);
        if (l == 0) e2[(size_t)b * 1600 + i * F_SZ + j] = s;
    }
}

// ---------------------------------------------------------------------------
// per b: softmax over 1600 e2's, rowsum/colsum, weighted feat sums (FP32 OUT)
// ---------------------------------------------------------------------------
__global__ __launch_bounds__(256) void k_out(
    const float* __restrict__ e2,
    const unsigned short* __restrict__ feat,
    float* __restrict__ out)                   // (32, 3072) FP32
{
    __shared__ float alpha[1600];
    __shared__ float red[4];
    __shared__ float rs[F_SZ], cs[F_SZ];
    const int b = blockIdx.x, t = threadIdx.x;
    const int w = t >> 6, l = t & 63;

    float lm = -1e30f;
    for (int idx = t; idx < 1600; idx += 256) {
        float v = e2[(size_t)b * 1600 + idx];
        alpha[idx] = v;
        lm = fmaxf(lm, v);
    }
#pragma unroll
    for (int off = 32; off; off >>= 1) lm = fmaxf(lm, __shfl_xor(lm, off));
    if (l == 0) red[w] = lm;
    __syncthreads();
    float M = fmaxf(fmaxf(red[0], red[1]), fmaxf(red[2], red[3]));
    __syncthreads();
    float ls = 0.f;
    for (int idx = t; idx < 1600; idx += 256) {
        float ex = expf(alpha[idx] - M);
        alpha[idx] = ex;
        ls += ex;
    }
#pragma unroll
    for (int off = 32; off; off >>= 1) ls += __shfl_xor(ls, off);
    if (l == 0) red[w] = ls;
    __syncthreads();
    float inv = 1.f / (red[0] + red[1] + red[2] + red[3]);

    if (t < F_SZ) {
        float s = 0.f;
        for (int j = 0; j < F_SZ; j++) s += alpha[t * F_SZ + j];
        rs[t] = s * inv;
    } else if (t >= 128 && t < 128 + F_SZ) {
        int j = t - 128;
        float s = 0.f;
        for (int i2 = 0; i2 < F_SZ; i2++) s += alpha[i2 * F_SZ + j];
        cs[j] = s * inv;
    }
    __syncthreads();

    float a1[6] = {0.f,0.f,0.f,0.f,0.f,0.f};
    float a2[6] = {0.f,0.f,0.f,0.f,0.f,0.f};
    for (int r = 0; r < F_SZ; r++) {
        float w1 = cs[r], w2 = rs[r];
        const unsigned short* fr = feat + (size_t)(b * F_SZ + r) * D_SZ;
#pragma unroll
        for (int u = 0; u < 6; u++) {
            float f = bf2f(fr[t + u * 256]);
            a1[u] += w1 * f;
            a2[u] += w2 * f;
        }
    }
#pragma unroll
    for (int u = 0; u < 6; u++) {
        out[(size_t)b * 3072 + t + u * 256]        = a1[u];
        out[(size_t)b * 3072 + 1536 + t + u * 256] = a2[u];
    }
}

// ---------------------------------------------------------------------------
// Workspace layout (9,510,912 B total; within previous 9,695,232 budget):
//   0        hs   (64 KB)
//   65536    hr   (64 KB)
//   131072   p    (5,242,880)  -- also hosts, before pgemm writes it:
//              e1p at 131072 (737,280; dead after k_softatt)
//              Wsb at 4849664 (524,288; dead after k_e1_mfma)
//   5373952  e2   (204,800)
//   5578752  feat (3,932,160)
// ---------------------------------------------------------------------------
extern "C" void kernel_launch(void* const* d_in, const int* in_sizes, int n_in,
                              void* d_out, int out_size, void* d_ws, size_t ws_size,
                              hipStream_t stream) {
    const float* i3d    = (const float*)d_in[0];
    const float* objf   = (const float*)d_in[1];
    const float* hidden = (const float*)d_in[2];
    const float* Wsf    = (const float*)d_in[3];
    const float* bsf    = (const float*)d_in[4];
    const float* Wsh    = (const float*)d_in[5];
    const float* bsh    = (const float*)d_in[6];
    const float* was    = (const float*)d_in[7];
    const float* Wrf    = (const float*)d_in[8];
    const float* brf    = (const float*)d_in[9];
    const float* Wrh    = (const float*)d_in[10];
    const float* brh    = (const float*)d_in[11];
    const float* war    = (const float*)d_in[12];
    float* out = (float*)d_out;

    char* ws = (char*)d_ws;
    float* hs  = (float*)(ws);
    float* hr  = (float*)(ws + 65536);
    float* p   = (float*)(ws + 131072);
    float* e1p = (float*)(ws + 131072);              // inside p region (dead before pgemm)
    unsigned short* Wsb = (unsigned short*)(ws + 4849664);  // inside p region tail
    float* e2  = (float*)(ws + 5373952);
    unsigned short* feat = (unsigned short*)(ws + 5578752);

    k_cast<<<dim3(128), dim3(256), 0, stream>>>(Wsf, Wsb);
    k_hproj<<<dim3(256), dim3(256), 0, stream>>>(hidden, Wsh, bsh, bsf, Wrh, brh, brf, hs, hr);
    k_e1_mfma<<<dim3(1440), dim3(256), 0, stream>>>(objf, Wsb, was, hs, e1p);
    k_softatt<<<dim3(NROW), dim3(256), 0, stream>>>(objf, i3d, e1p, feat);
    k_pgemm_mfma<<<dim3(320), dim3(256), 0, stream>>>(feat, Wrf, p);
    k_e2<<<dim3(NROW), dim3(256), 0, stream>>>(p, hr, war, e2);
    k_out<<<dim3(B_SZ), dim3(256), 0, stream>>>(e2, feat, out);
}

// Round 3
// 284.665 us; speedup vs baseline: 1.4876x; 1.1506x over previous
//
#include <hip/hip_runtime.h>
#include <stdint.h>

// Problem constants
#define B_SZ 32
#define F_SZ 40
#define NB_SZ 36
#define R_SZ 512
#define H_SZ 512
#define D_SZ 1536
#define M1 (B_SZ * F_SZ * NB_SZ)   // 46080
#define NROW (B_SZ * F_SZ)         // 1280
#define FNB (F_SZ * NB_SZ)         // 1440

typedef __attribute__((ext_vector_type(8))) short short8;   // 8 bf16 (MFMA A/B frag)
typedef __attribute__((ext_vector_type(4))) float f32x4;    // MFMA C/D frag

__device__ __forceinline__ unsigned short f2bf(float f) {
    unsigned int x = __float_as_uint(f);
    return (unsigned short)((x + 0x7fffu + ((x >> 16) & 1u)) >> 16);  // RNE
}
__device__ __forceinline__ float bf2f(unsigned short u) {
    union { unsigned int i; float f; } v; v.i = ((unsigned int)u) << 16; return v.f;
}
__device__ __forceinline__ unsigned int cvtpk(float lo, float hi) {
    unsigned int r;
    asm("v_cvt_pk_bf16_f32 %0, %1, %2" : "=v"(r) : "v"(lo), "v"(hi));
    return r;
}
__device__ __forceinline__ float fast_rcp(float x) {
    float r; asm("v_rcp_f32 %0, %1" : "=v"(r) : "v"(x)); return r;
}
__device__ __forceinline__ float fast_tanh(float x) {
    float cx = fminf(fmaxf(x, -9.0f), 9.0f);
    float e = __expf(2.0f * cx);
    return (e - 1.0f) * fast_rcp(e + 1.0f);
}

// direct-to-LDS 16B DMA: wave-uniform LDS base + lane*16; per-lane global src
__device__ __forceinline__ void gload_lds16(const void* gsrc, void* ldst) {
    __builtin_amdgcn_global_load_lds(
        (const __attribute__((address_space(1))) unsigned int*)gsrc,
        (__attribute__((address_space(3))) unsigned int*)ldst, 16, 0, 0);
}

// ---------------------------------------------------------------------------
// merged: blocks 0..255 -> hproj; blocks 256..383 -> Wsb = bf16(Wsf)
// ---------------------------------------------------------------------------
__global__ __launch_bounds__(256) void k_pre(
    const float* __restrict__ hidden,
    const float* __restrict__ Wsh, const float* __restrict__ bsh,
    const float* __restrict__ bsf,
    const float* __restrict__ Wrh, const float* __restrict__ brh,
    const float* __restrict__ brf,
    float* __restrict__ hs, float* __restrict__ hr,
    const float* __restrict__ Wsf, unsigned short* __restrict__ Wsb)
{
    const int t = threadIdx.x;
    if (blockIdx.x >= 256) {
        int i = ((blockIdx.x - 256) * 256 + t) * 8;
        float4 f0 = *(const float4*)(Wsf + i);
        float4 f1 = *(const float4*)(Wsf + i + 4);
        uint4 pk = {cvtpk(f0.x, f0.y), cvtpk(f0.z, f0.w),
                    cvtpk(f1.x, f1.y), cvtpk(f1.z, f1.w)};
        *(uint4*)(Wsb + i) = pk;
        return;
    }
    __shared__ float hid[H_SZ];
    const int b = blockIdx.x >> 3, hc = blockIdx.x & 7;
    for (int i = t; i < H_SZ; i += 256) hid[i] = hidden[b * H_SZ + i];
    __syncthreads();
    const int h = hc * 64 + (t >> 2), kq = t & 3;
    const float* r1 = Wsh + (size_t)h * H_SZ + kq * 128;
    const float* r2 = Wrh + (size_t)h * H_SZ + kq * 128;
    const float* hh = hid + kq * 128;
    float a1 = 0.f, a2 = 0.f;
    for (int k = 0; k < 128; k += 4) {
        float4 v1 = *(const float4*)(r1 + k);
        float4 v2 = *(const float4*)(r2 + k);
        a1 += hh[k] * v1.x + hh[k+1] * v1.y + hh[k+2] * v1.z + hh[k+3] * v1.w;
        a2 += hh[k] * v2.x + hh[k+1] * v2.y + hh[k+2] * v2.z + hh[k+3] * v2.w;
    }
    a1 += __shfl_xor(a1, 1); a1 += __shfl_xor(a1, 2);
    a2 += __shfl_xor(a2, 1); a2 += __shfl_xor(a2, 2);
    if (kq == 0) {
        hs[b * H_SZ + h] = a1 + bsh[h] + bsf[h];
        hr[b * H_SZ + h] = a2 + brh[h] + brf[h];
    }
}

// ---------------------------------------------------------------------------
// e1 partials: block = 128 m x 128 h, BK=64, double-buffered, 1 barrier/iter.
// A: fp32->bf16 reg-staged (loads issued before compute of current tile).
// B: bf16 via global_load_lds, source pre-swizzled (T21), LDS dest linear.
// e1p[by][m] = sum_{h in tile} tanh(S[m,h] + hs[b(m),h]) * was[h]
// ---------------------------------------------------------------------------
__global__ __launch_bounds__(256) void k_e1_mfma(
    const float* __restrict__ feats,        // (46080, 512) fp32
    const unsigned short* __restrict__ Wsb, // (512, 512) bf16
    const float* __restrict__ was,
    const float* __restrict__ hs,
    float* __restrict__ e1p)                // (4, 46080) fp32
{
    __shared__ __align__(16) unsigned char As[2][128 * 128];  // 16 KB each
    __shared__ __align__(16) unsigned char Bs[2][128 * 128];
    __shared__ float hsl[2 * 128];
    __shared__ float wasl[128];
    __shared__ float eps[2][128];

    // bijective XCD swizzle: 1440 = 8*180; 4 by-siblings adjacent on one XCD
    const int bx = blockIdx.x;
    const int wid = (bx & 7) * 180 + (bx >> 3);
    const int mb = wid >> 2, by = wid & 3;
    const int m0 = mb * 128, hb = by * 128;
    const int t = threadIdx.x;
    const int b0 = m0 / FNB, b1 = (m0 + 127) / FNB;
    const int thr = (b0 + 1) * FNB - m0;

    if (t < 128) {
        hsl[t]       = hs[b0 * H_SZ + hb + t];
        hsl[128 + t] = hs[b1 * H_SZ + hb + t];
        wasl[t]      = was[hb + t];
    }

    const int lane = t & 63, w = t >> 6;
    const int wr = w >> 1, wc = w & 1;
    const int l15 = lane & 15, lk = lane >> 4;

    int ar[4], brw[4];
#pragma unroll
    for (int i = 0; i < 4; i++) {
        ar[i]  = wr * 64 + i * 16 + l15;
        brw[i] = wc * 64 + i * 16 + l15;
    }

    // staging geometry
    const int srow = t >> 3;       // 0..31 (+ it*32)
    const int scol = t & 7;        // chunk of 8 elems (16 B)
    const int wub  = (t & 192) * 16;  // wave-uniform LDS sub-base

    float4 alo[4], ahi[4];
    f32x4 acc[4][4] = {};
    float ep[4][4] = {{0.f}};

#define E1_LOAD_A(K0) do { \
    _Pragma("unroll") \
    for (int it = 0; it < 4; it++) { \
        int r = it * 32 + srow; \
        const float* src = feats + (size_t)(m0 + r) * R_SZ + (K0) + scol * 8; \
        alo[it] = *(const float4*)src; \
        ahi[it] = *(const float4*)(src + 4); \
    } } while (0)

#define E1_STAGE_B(BUF, K0) do { \
    _Pragma("unroll") \
    for (int it = 0; it < 4; it++) { \
        int r = it * 32 + srow; \
        int gc = scol ^ (r & 7); \
        gload_lds16(Wsb + (size_t)(hb + r) * R_SZ + (K0) + gc * 8, \
                    &Bs[BUF][it * 4096 + wub]); \
    } } while (0)

#define E1_WRITE_A(BUF) do { \
    _Pragma("unroll") \
    for (int it = 0; it < 4; it++) { \
        int r = it * 32 + srow; \
        uint4 pk = {cvtpk(alo[it].x, alo[it].y), cvtpk(alo[it].z, alo[it].w), \
                    cvtpk(ahi[it].x, ahi[it].y), cvtpk(ahi[it].z, ahi[it].w)}; \
        *(uint4*)(&As[BUF][r * 128 + ((scol ^ (r & 7)) << 4)]) = pk; \
    } } while (0)

#define E1_COMPUTE(BUF) do { \
    _Pragma("unroll") \
    for (int ks = 0; ks < 2; ks++) { \
        short8 a[4], bv[4]; \
        int c = ks * 4 + lk; \
        _Pragma("unroll") \
        for (int i = 0; i < 4; i++) { \
            a[i]  = *(const short8*)(&As[BUF][ar[i]  * 128 + ((c ^ (ar[i]  & 7)) << 4)]); \
            bv[i] = *(const short8*)(&Bs[BUF][brw[i] * 128 + ((c ^ (brw[i] & 7)) << 4)]); \
        } \
        _Pragma("unroll") \
        for (int i = 0; i < 4; i++) \
        _Pragma("unroll") \
        for (int j = 0; j < 4; j++) \
            acc[i][j] = __builtin_amdgcn_mfma_f32_16x16x32_bf16(a[i], bv[j], acc[i][j], 0, 0, 0); \
    } } while (0)

    // prologue: fill buffer 0
    E1_LOAD_A(0);
    E1_STAGE_B(0, 0);
    E1_WRITE_A(0);
    __syncthreads();   // drains gloads + ds_writes (vmcnt0+lgkmcnt0 implied)

    for (int ki = 0; ki < 8; ki++) {
        int cur = ki & 1, nxt = cur ^ 1;
        if (ki < 7) {
            E1_LOAD_A((ki + 1) * 64);       // issue early: latency hides under MFMA
            E1_STAGE_B(nxt, (ki + 1) * 64);
        }
        E1_COMPUTE(cur);
        if (ki < 7) E1_WRITE_A(nxt);
        __syncthreads();
    }

    // epilogue: tanh + was-weighted row partials
#pragma unroll
    for (int j = 0; j < 4; j++) {
        int hl = wc * 64 + j * 16 + l15;
        float wv = wasl[hl];
#pragma unroll
        for (int i = 0; i < 4; i++) {
#pragma unroll
            for (int q = 0; q < 4; q++) {
                int r = wr * 64 + i * 16 + lk * 4 + q;
                float hv = hsl[(r >= thr ? 128 : 0) + hl];
                ep[i][q] += fast_tanh(acc[i][j][q] + hv) * wv;
            }
        }
    }
#pragma unroll
    for (int i = 0; i < 4; i++)
#pragma unroll
        for (int q = 0; q < 4; q++) {
            float v = ep[i][q];
            v += __shfl_xor(v, 1);
            v += __shfl_xor(v, 2);
            v += __shfl_xor(v, 4);
            v += __shfl_xor(v, 8);
            if (l15 == 0) eps[wc][wr * 64 + i * 16 + lk * 4 + q] = v;
        }
    __syncthreads();
    if (t < 128) e1p[(size_t)by * M1 + m0 + t] = eps[0][t] + eps[1][t];
#undef E1_LOAD_A
#undef E1_STAGE_B
#undef E1_WRITE_A
#undef E1_COMPUTE
}

// ---------------------------------------------------------------------------
// per n: softmax over 36 e1's (sum of 4 partials), att = alpha-weighted sum,
// feat[n] = [att(512) | i3d(1024)] bf16
// ---------------------------------------------------------------------------
__global__ __launch_bounds__(256) void k_softatt(
    const float* __restrict__ feats,
    const float* __restrict__ i3d,
    const float* __restrict__ e1p,
    unsigned short* __restrict__ feat)
{
    __shared__ float alpha[NB_SZ];
    const int n = blockIdx.x, t = threadIdx.x;
    if (t < 64) {
        float v = -1e30f;
        if (t < NB_SZ) {
            int idx = n * NB_SZ + t;
            v = e1p[idx] + e1p[M1 + idx] + e1p[2 * M1 + idx] + e1p[3 * M1 + idx];
        }
        float m = v;
#pragma unroll
        for (int off = 32; off; off >>= 1) m = fmaxf(m, __shfl_xor(m, off));
        float ex = (t < NB_SZ) ? expf(v - m) : 0.f;
        float ssum = ex;
#pragma unroll
        for (int off = 32; off; off >>= 1) ssum += __shfl_xor(ssum, off);
        if (t < NB_SZ) alpha[t] = ex / ssum;
    }
    __syncthreads();

    float a0 = 0.f, a1 = 0.f;
    const float* base = feats + (size_t)n * NB_SZ * R_SZ;
    for (int ll = 0; ll < NB_SZ; ll++) {
        float al = alpha[ll];
        float2 pv = *(const float2*)(base + ll * R_SZ + 2 * t);
        a0 += al * pv.x;
        a1 += al * pv.y;
    }
    feat[(size_t)n * D_SZ + 2 * t]     = f2bf(a0);
    feat[(size_t)n * D_SZ + 2 * t + 1] = f2bf(a1);
    float4 iv = *(const float4*)(i3d + (size_t)n * 1024 + t * 4);
    unsigned short o[4] = {f2bf(iv.x), f2bf(iv.y), f2bf(iv.z), f2bf(iv.w)};
    *(uint2*)(feat + (size_t)n * D_SZ + 512 + t * 4) = *(const uint2*)o;
}

// ---------------------------------------------------------------------------
// p[n, j] = feat[n,:] @ Wr_f-row(j); tile 64m x 32n, BK=64, double-buffered.
// A: feat bf16 via global_load_lds (pre-swizzled source).
// B: Wrf fp32 reg-staged -> bf16. 640 blocks, ~24 KB LDS.
// ---------------------------------------------------------------------------
__global__ __launch_bounds__(256) void k_pgemm_mfma(
    const unsigned short* __restrict__ feat,  // (1280, 1536) bf16
    const float* __restrict__ Wrf,            // (512, 3072) fp32
    float* __restrict__ p)                    // (1280, 1024) fp32
{
    __shared__ __align__(16) unsigned char As[2][64 * 128];  // 8 KB each
    __shared__ __align__(16) unsigned char Bs[2][32 * 128];  // 4 KB each

    // bijective XCD swizzle: 640 = 8*80; n-major within XCD for Wrf L2 reuse
    const int bx = blockIdx.x;
    const int wid = (bx & 7) * 80 + (bx >> 3);
    const int mb = wid % 20, nb = wid / 20;
    const int m0 = mb * 64, j0 = nb * 32;
    const int t = threadIdx.x;

    const int lane = t & 63, w = t >> 6;
    const int wr = w >> 1, wc = w & 1;            // wave: 32m x 16n
    const int l15 = lane & 15, lk = lane >> 4;

    const int srow = t >> 3;       // 0..31
    const int scol = t & 7;
    const int wub  = (t & 192) * 16;

    const size_t brow_base = (j0 < 512) ? (size_t)j0 * 3072
                                        : ((size_t)(j0 - 512) * 3072 + 1536);

    int ar[2];
    ar[0] = wr * 32 + l15; ar[1] = ar[0] + 16;
    const int brow = wc * 16 + l15;

    float4 blo, bhi;
    f32x4 acc[2] = {};

#define PG_STAGE_A(BUF, K0) do { \
    _Pragma("unroll") \
    for (int it = 0; it < 2; it++) { \
        int r = it * 32 + srow; \
        int gc = scol ^ (r & 7); \
        gload_lds16(feat + (size_t)(m0 + r) * D_SZ + (K0) + gc * 8, \
                    &As[BUF][it * 4096 + wub]); \
    } } while (0)

#define PG_LOAD_B(K0) do { \
    const float* src = Wrf + brow_base + (size_t)srow * 3072 + (K0) + scol * 8; \
    blo = *(const float4*)src; \
    bhi = *(const float4*)(src + 4); \
    } while (0)

#define PG_WRITE_B(BUF) do { \
    uint4 pk = {cvtpk(blo.x, blo.y), cvtpk(blo.z, blo.w), \
                cvtpk(bhi.x, bhi.y), cvtpk(bhi.z, bhi.w)}; \
    *(uint4*)(&Bs[BUF][srow * 128 + ((scol ^ (srow & 7)) << 4)]) = pk; \
    } while (0)

#define PG_COMPUTE(BUF) do { \
    _Pragma("unroll") \
    for (int ks = 0; ks < 2; ks++) { \
        int c = ks * 4 + lk; \
        short8 a0 = *(const short8*)(&As[BUF][ar[0] * 128 + ((c ^ (ar[0] & 7)) << 4)]); \
        short8 a1 = *(const short8*)(&As[BUF][ar[1] * 128 + ((c ^ (ar[1] & 7)) << 4)]); \
        short8 bv = *(const short8*)(&Bs[BUF][brow  * 128 + ((c ^ (brow  & 7)) << 4)]); \
        acc[0] = __builtin_amdgcn_mfma_f32_16x16x32_bf16(a0, bv, acc[0], 0, 0, 0); \
        acc[1] = __builtin_amdgcn_mfma_f32_16x16x32_bf16(a1, bv, acc[1], 0, 0, 0); \
    } } while (0)

    // prologue
    PG_LOAD_B(0);
    PG_STAGE_A(0, 0);
    PG_WRITE_B(0);
    __syncthreads();

    for (int ki = 0; ki < 24; ki++) {
        int cur = ki & 1, nxt = cur ^ 1;
        if (ki < 23) {
            PG_LOAD_B((ki + 1) * 64);
            PG_STAGE_A(nxt, (ki + 1) * 64);
        }
        PG_COMPUTE(cur);
        if (ki < 23) PG_WRITE_B(nxt);
        __syncthreads();
    }

#pragma unroll
    for (int i = 0; i < 2; i++)
#pragma unroll
        for (int q = 0; q < 4; q++) {
            int row = m0 + wr * 32 + i * 16 + lk * 4 + q;
            int col = j0 + wc * 16 + l15;
            p[(size_t)row * 1024 + col] = acc[i][q];
        }
#undef PG_STAGE_A
#undef PG_LOAD_B
#undef PG_WRITE_B
#undef PG_COMPUTE
}

// ---------------------------------------------------------------------------
// e2[b,i,j] = sum_d tanh(p2[b*F+i,d] + p1[b*F+j,d] + hr[b,d]) * war[d]
// ---------------------------------------------------------------------------
__global__ __launch_bounds__(256) void k_e2(
    const float* __restrict__ p,
    const float* __restrict__ hr,
    const float* __restrict__ war,
    float* __restrict__ e2)
{
    const int blk = blockIdx.x;
    const int b = blk / F_SZ, i = blk % F_SZ;
    const int t = threadIdx.x;
    const int w = t >> 6, l = t & 63;
    const int ni = b * F_SZ + i;

    float base[8], warf[8];
    {
        float4 pa = *(const float4*)(p + (size_t)ni * 1024 + 512 + l * 8);
        float4 pb = *(const float4*)(p + (size_t)ni * 1024 + 512 + l * 8 + 4);
        float4 ha = *(const float4*)(hr + b * H_SZ + l * 8);
        float4 hb = *(const float4*)(hr + b * H_SZ + l * 8 + 4);
        base[0] = pa.x + ha.x; base[1] = pa.y + ha.y; base[2] = pa.z + ha.z; base[3] = pa.w + ha.w;
        base[4] = pb.x + hb.x; base[5] = pb.y + hb.y; base[6] = pb.z + hb.z; base[7] = pb.w + hb.w;
        float4 wa = *(const float4*)(war + l * 8);
        float4 wb = *(const float4*)(war + l * 8 + 4);
        warf[0] = wa.x; warf[1] = wa.y; warf[2] = wa.z; warf[3] = wa.w;
        warf[4] = wb.x; warf[5] = wb.y; warf[6] = wb.z; warf[7] = wb.w;
    }

    for (int j = w; j < F_SZ; j += 4) {
        const float* p1r = p + (size_t)(b * F_SZ + j) * 1024;
        float4 va = *(const float4*)(p1r + l * 8);
        float4 vb = *(const float4*)(p1r + l * 8 + 4);
        float pv[8] = {va.x, va.y, va.z, va.w, vb.x, vb.y, vb.z, vb.w};
        float s = 0.f;
#pragma unroll
        for (int u = 0; u < 8; u++) s += fast_tanh(pv[u] + base[u]) * warf[u];
#pragma unroll
        for (int off = 32; off; off >>= 1) s += __shfl_xor(s, off);
        if (l == 0) e2[(size_t)b * 1600 + i * F_SZ + j] = s;
    }
}

// ---------------------------------------------------------------------------
// per b: softmax over 1600 e2's, rowsum/colsum, weighted feat sums (FP32 OUT)
// ---------------------------------------------------------------------------
__global__ __launch_bounds__(256) void k_out(
    const float* __restrict__ e2,
    const unsigned short* __restrict__ feat,
    float* __restrict__ out)                   // (32, 3072) FP32
{
    __shared__ float alpha[1600];
    __shared__ float red[4];
    __shared__ float rs[F_SZ], cs[F_SZ];
    const int b = blockIdx.x, t = threadIdx.x;
    const int w = t >> 6, l = t & 63;

    float lm = -1e30f;
    for (int idx = t; idx < 1600; idx += 256) {
        float v = e2[(size_t)b * 1600 + idx];
        alpha[idx] = v;
        lm = fmaxf(lm, v);
    }
#pragma unroll
    for (int off = 32; off; off >>= 1) lm = fmaxf(lm, __shfl_xor(lm, off));
    if (l == 0) red[w] = lm;
    __syncthreads();
    float M = fmaxf(fmaxf(red[0], red[1]), fmaxf(red[2], red[3]));
    __syncthreads();
    float ls = 0.f;
    for (int idx = t; idx < 1600; idx += 256) {
        float ex = expf(alpha[idx] - M);
        alpha[idx] = ex;
        ls += ex;
    }
#pragma unroll
    for (int off = 32; off; off >>= 1) ls += __shfl_xor(ls, off);
    if (l == 0) red[w] = ls;
    __syncthreads();
    float inv = 1.f / (red[0] + red[1] + red[2] + red[3]);

    if (t < F_SZ) {
        float s = 0.f;
        for (int j = 0; j < F_SZ; j++) s += alpha[t * F_SZ + j];
        rs[t] = s * inv;
    } else if (t >= 128 && t < 128 + F_SZ) {
        int j = t - 128;
        float s = 0.f;
        for (int i2 = 0; i2 < F_SZ; i2++) s += alpha[i2 * F_SZ + j];
        cs[j] = s * inv;
    }
    __syncthreads();

    float a1[6] = {0.f,0.f,0.f,0.f,0.f,0.f};
    float a2[6] = {0.f,0.f,0.f,0.f,0.f,0.f};
    for (int r = 0; r < F_SZ; r++) {
        float w1 = cs[r], w2 = rs[r];
        const unsigned short* fr = feat + (size_t)(b * F_SZ + r) * D_SZ;
#pragma unroll
        for (int u = 0; u < 6; u++) {
            float f = bf2f(fr[t + u * 256]);
            a1[u] += w1 * f;
            a2[u] += w2 * f;
        }
    }
#pragma unroll
    for (int u = 0; u < 6; u++) {
        out[(size_t)b * 3072 + t + u * 256]        = a1[u];
        out[(size_t)b * 3072 + 1536 + t + u * 256] = a2[u];
    }
}

// ---------------------------------------------------------------------------
// Workspace layout (9,510,912 B total):
//   0        hs   (64 KB)
//   65536    hr   (64 KB)
//   131072   p    (5,242,880)  -- also hosts, before pgemm writes it:
//              e1p at 131072 (737,280; dead after k_softatt)
//              Wsb at 4849664 (524,288; dead after k_e1_mfma)
//   5373952  e2   (204,800)
//   5578752  feat (3,932,160)
// ---------------------------------------------------------------------------
extern "C" void kernel_launch(void* const* d_in, const int* in_sizes, int n_in,
                              void* d_out, int out_size, void* d_ws, size_t ws_size,
                              hipStream_t stream) {
    const float* i3d    = (const float*)d_in[0];
    const float* objf   = (const float*)d_in[1];
    const float* hidden = (const float*)d_in[2];
    const float* Wsf    = (const float*)d_in[3];
    const float* bsf    = (const float*)d_in[4];
    const float* Wsh    = (const float*)d_in[5];
    const float* bsh    = (const float*)d_in[6];
    const float* was    = (const float*)d_in[7];
    const float* Wrf    = (const float*)d_in[8];
    const float* brf    = (const float*)d_in[9];
    const float* Wrh    = (const float*)d_in[10];
    const float* brh    = (const float*)d_in[11];
    const float* war    = (const float*)d_in[12];
    float* out = (float*)d_out;

    char* ws = (char*)d_ws;
    float* hs  = (float*)(ws);
    float* hr  = (float*)(ws + 65536);
    float* p   = (float*)(ws + 131072);
    float* e1p = (float*)(ws + 131072);                     // inside p (dead before pgemm)
    unsigned short* Wsb = (unsigned short*)(ws + 4849664);  // inside p tail
    float* e2  = (float*)(ws + 5373952);
    unsigned short* feat = (unsigned short*)(ws + 5578752);

    k_pre<<<dim3(384), dim3(256), 0, stream>>>(hidden, Wsh, bsh, bsf, Wrh, brh, brf, hs, hr, Wsf, Wsb);
    k_e1_mfma<<<dim3(1440), dim3(256), 0, stream>>>(objf, Wsb, was, hs, e1p);
    k_softatt<<<dim3(NROW), dim3(256), 0, stream>>>(objf, i3d, e1p, feat);
    k_pgemm_mfma<<<dim3(640), dim3(256), 0, stream>>>(feat, Wrf, p);
    k_e2<<<dim3(NROW), dim3(256), 0, stream>>>(p, hr, war, e2);
    k_out<<<dim3(B_SZ), dim3(256), 0, stream>>>(e2, feat, out);
}